// Round 6
// baseline (1250.209 us; speedup 1.0000x reference)
//
#include <hip/hip_runtime.h>
#include <hip/hip_bf16.h>

// ---------------------------------------------------------------------------
// GCN restructured via associativity:  spmm(H) @ W == spmm(H @ W)
//   D0 = X @ W0T          ; A = gelu(spmm(D0) + b0)
//   D1 = A @ W1T          ; B = gelu(spmm(D1) + b1)
//   D2 = B @ W2T (128-w)  ; out = spmm(D2) + b2     <- final spmm 128-wide
// fp32 everywhere (bf16 intermediate would blow the 1.3e-3 threshold).
// dense k-loop: weights software-prefetched 1 group ahead (8 loads in
// flight), input broadcast via ds_read_b128 (4 k's per read).
// ---------------------------------------------------------------------------

typedef float f32x4 __attribute__((ext_vector_type(4)));
typedef float f32x2 __attribute__((ext_vector_type(2)));

__device__ __forceinline__ float gelu_fast(float x) {
    // 0.5x(1+tanh(u)) == x * sigmoid(2u); one hw exp instead of sw tanh
    float u = 0.7978845608028654f * (x + 0.044715f * x * x * x);
    return x / (1.0f + __expf(-2.0f * u));
}

__global__ void count_kernel(const int* __restrict__ row, int* __restrict__ cnt, int e) {
    int i = blockIdx.x * blockDim.x + threadIdx.x;
    if (i < e) atomicAdd(&cnt[row[i]], 1);
}

__global__ void rnorm_kernel(const int* __restrict__ cnt, float* __restrict__ rnorm, int n) {
    int i = blockIdx.x * blockDim.x + threadIdx.x;
    if (i < n) rnorm[i] = rsqrtf((float)(cnt[i] + 1));
}

__global__ void scan1_kernel(const int* __restrict__ cnt, int* __restrict__ rowptr,
                             int* __restrict__ bsum, int n) {
    __shared__ int s[1024];
    int t = threadIdx.x;
    int i = blockIdx.x * 1024 + t;
    int v = (i < n) ? cnt[i] : 0;
    s[t] = v;
    __syncthreads();
    for (int off = 1; off < 1024; off <<= 1) {
        int x = (t >= off) ? s[t - off] : 0;
        __syncthreads();
        s[t] += x;
        __syncthreads();
    }
    if (i < n) rowptr[i] = s[t] - v;
    if (t == 1023) bsum[blockIdx.x] = s[1023];
}

__global__ void scan2_kernel(int* bsum, int nb) {
    if (threadIdx.x == 0 && blockIdx.x == 0) {
        int a = 0;
        for (int b = 0; b < nb; ++b) { int v = bsum[b]; bsum[b] = a; a += v; }
    }
}

__global__ void scan3_kernel(int* __restrict__ rowptr, const int* __restrict__ bsum, int n, int e) {
    int i = blockIdx.x * blockDim.x + threadIdx.x;
    if (i < n) rowptr[i] += bsum[i >> 10];
    if (i == 0) rowptr[n] = e;
}

__global__ void fill_kernel(const int* __restrict__ row, const int* __restrict__ col,
                            const int* __restrict__ rowptr, int* __restrict__ fillc,
                            const float* __restrict__ rnorm,
                            int2* __restrict__ meta, int e) {
    int i = blockIdx.x * blockDim.x + threadIdx.x;
    if (i >= e) return;
    int r = row[i], c = col[i];
    int pos = rowptr[r] + atomicAdd(&fillc[r], 1);
    float w = rnorm[r] * rnorm[c];
    meta[pos] = make_int2(c, __float_as_int(w));
}

__global__ void transpose_kernel(const float* __restrict__ w, float* __restrict__ wt,
                                 int dout, int din, int total) {
    int i = blockIdx.x * blockDim.x + threadIdx.x;
    if (i < total) {
        int k = i / dout, c = i % dout;   // wt[k][c] = w[c][k]
        wt[i] = w[c * din + k];
    }
}

template <int WPL> struct VecT;
template <> struct VecT<4> { using T = f32x4; };
template <> struct VecT<2> { using T = f32x2; };

// one wave per row; 64 lanes x WPL floats. Bias (+ optional gelu) fused.
// meta batches software-pipelined.
template <int WPL, bool GELU>
__global__ __launch_bounds__(256) void spmm_kernel(const float* __restrict__ in,
                                                   float* __restrict__ out,
                                                   const int* __restrict__ rowptr,
                                                   const int2* __restrict__ meta,
                                                   const float* __restrict__ rnorm,
                                                   const float* __restrict__ bias, int n) {
    using vec_t = typename VecT<WPL>::T;
    constexpr int RW = 64 * WPL;
    int wid = blockIdx.x * 4 + (threadIdx.x >> 6);
    if (wid >= n) return;
    int lane = threadIdx.x & 63;
    const float* lanebase = in + lane * WPL;

    float rn = rnorm[wid];
    float sw = rn * rn;   // self-loop weight
    float acc[WPL];
    {
        vec_t a = *(const vec_t*)(lanebase + (size_t)wid * RW);
#pragma unroll
        for (int q = 0; q < WPL; ++q) acc[q] = sw * a[q];
    }

    int e0 = rowptr[wid], e1 = rowptr[wid + 1];
    int e = e0;
    int nbatch = (e1 - e0) >> 3;
    if (nbatch > 0) {
        int2 m[8];
#pragma unroll
        for (int u = 0; u < 8; ++u) m[u] = meta[e + u];
        for (int b = 0; b < nbatch; ++b) {
            vec_t v[8];
#pragma unroll
            for (int u = 0; u < 8; ++u) v[u] = *(const vec_t*)(lanebase + (size_t)m[u].x * RW);
            int2 mn[8];
            bool more = (b + 1 < nbatch);
            if (more) {
#pragma unroll
                for (int u = 0; u < 8; ++u) mn[u] = meta[e + 8 + u];
            }
#pragma unroll
            for (int u = 0; u < 8; ++u) {
                float w = __int_as_float(m[u].y);
#pragma unroll
                for (int q = 0; q < WPL; ++q) acc[q] = fmaf(w, v[u][q], acc[q]);
            }
            if (more) {
#pragma unroll
                for (int u = 0; u < 8; ++u) m[u] = mn[u];
            }
            e += 8;
        }
    }
    for (; e < e1; ++e) {
        int2 m = meta[e];
        vec_t v = *(const vec_t*)(lanebase + (size_t)m.x * RW);
        float w = __int_as_float(m.y);
#pragma unroll
        for (int q = 0; q < WPL; ++q) acc[q] = fmaf(w, v[q], acc[q]);
    }

    vec_t bv = *(const vec_t*)(bias + lane * WPL);
    vec_t o;
#pragma unroll
    for (int q = 0; q < WPL; ++q) {
        float x = acc[q] + bv[q];
        o[q] = GELU ? gelu_fast(x) : x;
    }
    __builtin_nontemporal_store(o, (vec_t*)(out + (size_t)wid * RW + lane * WPL));
}

// dense: out[N][DO] = in[N][256] @ WT[256][DO]. No bias/gelu (fused into spmm).
// 4 waves per block partition the DO columns; K walked in groups of 4:
//  - weights for group g+1 loaded while group g computes (8 loads in flight
//    with unroll 2) -> L2 latency hidden
//  - input broadcast read as ds_read_b128 (rows stride 260 floats -> banks
//    4 apart, conflict-free)
template <int DO>
__global__ __launch_bounds__(256, 4) void dense_kernel(const float* __restrict__ in,
                                                       const float* __restrict__ wt,
                                                       float* __restrict__ out) {
    constexpr int BM = 32;
    constexpr int LDR = 260;        // floats; %4==0 so b128 reads stay aligned
    constexpr int TCW = DO / 16;    // col-threads per wave: 16 (256) / 8 (128)
    constexpr int TRW = 64 / TCW;   // row-threads per wave: 4 / 8
    constexpr int RPT = BM / TRW;   // rows per thread: 8 / 4
    constexpr int WCOLS = DO / 4;   // cols per wave: 64 / 32
    __shared__ float s_in[BM * LDR];

    int t = threadIdx.x;
    int w = t >> 6;
    int lane = t & 63;
    int row0 = blockIdx.x * BM;

    // stage 32x256 input tile: coalesced nt reads, conflict-free f32x4 writes
    const f32x4* gin = (const f32x4*)(in + (size_t)row0 * 256);
#pragma unroll
    for (int i = 0; i < (BM * 64) / 256; ++i) {   // 8 iters
        int idx = t + i * 256;
        int r = idx >> 6, k4 = idx & 63;
        f32x4 val = __builtin_nontemporal_load(gin + idx);
        *(f32x4*)&s_in[r * LDR + k4 * 4] = val;
    }
    __syncthreads();

    int tc = lane % TCW;
    int tr = lane / TCW;
    int c0 = w * WCOLS + tc * 4;          // this thread's 4 output cols
    const float* wbase = wt + c0;         // wt[k][c0..c0+3] = wbase + k*DO

    float acc[RPT][4];
#pragma unroll
    for (int j = 0; j < RPT; ++j)
#pragma unroll
        for (int q = 0; q < 4; ++q) acc[j][q] = 0.0f;

    // k-groups of 4, weights prefetched one group ahead
    f32x4 wreg[4];
#pragma unroll
    for (int q = 0; q < 4; ++q) wreg[q] = *(const f32x4*)(wbase + (size_t)q * DO);

#pragma unroll 2
    for (int g = 0; g < 64; ++g) {
        f32x4 wnext[4];
        if (g < 63) {
#pragma unroll
            for (int q = 0; q < 4; ++q)
                wnext[q] = *(const f32x4*)(wbase + (size_t)(4 * g + 4 + q) * DO);
        }
        f32x4 iv[RPT];
#pragma unroll
        for (int j = 0; j < RPT; ++j)
            iv[j] = *(const f32x4*)&s_in[(tr + j * TRW) * LDR + 4 * g];   // b128
#pragma unroll
        for (int q = 0; q < 4; ++q) {
#pragma unroll
            for (int j = 0; j < RPT; ++j) {
                acc[j][0] = fmaf(iv[j][q], wreg[q].x, acc[j][0]);
                acc[j][1] = fmaf(iv[j][q], wreg[q].y, acc[j][1]);
                acc[j][2] = fmaf(iv[j][q], wreg[q].z, acc[j][2]);
                acc[j][3] = fmaf(iv[j][q], wreg[q].w, acc[j][3]);
            }
        }
#pragma unroll
        for (int q = 0; q < 4; ++q) wreg[q] = wnext[q];
    }

#pragma unroll
    for (int j = 0; j < RPT; ++j) {
        int r = row0 + tr + j * TRW;
        f32x4 o = { acc[j][0], acc[j][1], acc[j][2], acc[j][3] };
        *(f32x4*)&out[(size_t)r * DO + c0] = o;
    }
}

extern "C" void kernel_launch(void* const* d_in, const int* in_sizes, int n_in,
                              void* d_out, int out_size, void* d_ws, size_t ws_size,
                              hipStream_t stream) {
    const float* X  = (const float*)d_in[0];
    const int* row  = (const int*)d_in[1];
    const int* col  = (const int*)d_in[2];
    const float* W0 = (const float*)d_in[3];
    const float* b0 = (const float*)d_in[4];
    const float* W1 = (const float*)d_in[5];
    const float* b1 = (const float*)d_in[6];
    const float* W2 = (const float*)d_in[7];
    const float* b2 = (const float*)d_in[8];

    int n = in_sizes[0] / 256;   // 100000
    int e = in_sizes[1];         // 1600000

    char* ws = (char*)d_ws;
    size_t off = 0;
    auto alloc = [&](size_t bytes) {
        void* p = ws + off;
        off += (bytes + 255) & ~(size_t)255;
        return p;
    };
    float* A      = (float*)alloc((size_t)n * 256 * 4);
    float* B      = (float*)alloc((size_t)n * 256 * 4);
    float* WT0    = (float*)alloc(256 * 256 * 4);
    float* WT1    = (float*)alloc(256 * 256 * 4);
    float* WT2    = (float*)alloc(256 * 128 * 4);
    int*   cnt    = (int*)alloc((size_t)n * 4);
    int*   fillc  = (int*)alloc((size_t)n * 4);
    float* rnorm  = (float*)alloc((size_t)n * 4);
    int*   rowptr = (int*)alloc(((size_t)n + 1) * 4);
    int*   bsum   = (int*)alloc(512);
    int2*  meta   = (int2*)alloc((size_t)e * 8);

    (void)hipMemsetAsync(cnt, 0, (size_t)n * 4, stream);
    (void)hipMemsetAsync(fillc, 0, (size_t)n * 4, stream);

    int gE = (e + 255) / 256;
    int gN = (n + 255) / 256;
    int nb = (n + 1023) / 1024;

    count_kernel<<<gE, 256, 0, stream>>>(row, cnt, e);
    rnorm_kernel<<<gN, 256, 0, stream>>>(cnt, rnorm, n);
    scan1_kernel<<<nb, 1024, 0, stream>>>(cnt, rowptr, bsum, n);
    scan2_kernel<<<1, 64, 0, stream>>>(bsum, nb);
    scan3_kernel<<<gN, 256, 0, stream>>>(rowptr, bsum, n, e);
    fill_kernel<<<gE, 256, 0, stream>>>(row, col, rowptr, fillc, rnorm, meta, e);

    transpose_kernel<<<(256 * 256) / 256, 256, 0, stream>>>(W0, WT0, 256, 256, 256 * 256);
    transpose_kernel<<<(256 * 256) / 256, 256, 0, stream>>>(W1, WT1, 256, 256, 256 * 256);
    transpose_kernel<<<(256 * 128) / 256, 256, 0, stream>>>(W2, WT2, 128, 256, 256 * 128);

    int gS = (n + 3) / 4;      // spmm: 4 waves/block, 1 row/wave
    int gD = n / 32;           // dense: 32 rows/block (100000 % 32 == 0)

    // D0 = X @ W0T ; A = gelu(spmm(D0) + b0)
    dense_kernel<256><<<gD, 256, 0, stream>>>(X, WT0, A);
    spmm_kernel<4, true><<<gS, 256, 0, stream>>>(A, B, rowptr, meta, rnorm, b0, n);
    // D1 = B @ W1T ; A = gelu(spmm(D1) + b1)
    dense_kernel<256><<<gD, 256, 0, stream>>>(B, WT1, A);
    spmm_kernel<4, true><<<gS, 256, 0, stream>>>(A, B, rowptr, meta, rnorm, b1, n);
    // D2 = B @ W2T (128 wide) ; out = spmm(D2) + b2
    dense_kernel<128><<<gD, 256, 0, stream>>>(B, WT2, A);
    spmm_kernel<2, false><<<gS, 256, 0, stream>>>(A, (float*)d_out, rowptr, meta, rnorm, b2, n);
}

// Round 7
// 1058.142 us; speedup vs baseline: 1.1815x; 1.1815x over previous
//
#include <hip/hip_runtime.h>
#include <hip/hip_bf16.h>

// ---------------------------------------------------------------------------
// GCN via associativity:  spmm(H) @ W == spmm(H @ W)
//   D0 = X @ W0T          ; A = gelu(spmm(D0) + b0)
//   D1 = A @ W1T          ; B = gelu(spmm(D1) + b1)
//   D2 = B @ W2T (128-w)  ; out = spmm(D2) + b2
// Dense layers on MFMA via split-bf16: x = hi + lo (bf16 each);
//   A@W ~= Ahi·Whi + Ahi·Wlo + Alo·Whi   (rel err ~2^-16, fp32 acc)
// Activations split fused into spmm epilogue; X split once; W split once.
// MFMA B-operand consumes W[n][k] natively (no transpose).
// ---------------------------------------------------------------------------

typedef float f32x4 __attribute__((ext_vector_type(4)));
typedef float f32x2 __attribute__((ext_vector_type(2)));
typedef short s16x4 __attribute__((ext_vector_type(4)));
typedef short bf16x8 __attribute__((ext_vector_type(8)));

__device__ __forceinline__ unsigned short f2bf(float x) {   // RNE
    unsigned u = __float_as_uint(x);
    return (unsigned short)((u + 0x7fff + ((u >> 16) & 1)) >> 16);
}
__device__ __forceinline__ float bf2f(unsigned short b) {
    return __uint_as_float(((unsigned)b) << 16);
}

__device__ __forceinline__ float gelu_fast(float x) {
    float u = 0.7978845608028654f * (x + 0.044715f * x * x * x);
    return x / (1.0f + __expf(-2.0f * u));
}

__global__ void count_kernel(const int* __restrict__ row, int* __restrict__ cnt, int e) {
    int i = blockIdx.x * blockDim.x + threadIdx.x;
    if (i < e) atomicAdd(&cnt[row[i]], 1);
}

__global__ void rnorm_kernel(const int* __restrict__ cnt, float* __restrict__ rnorm, int n) {
    int i = blockIdx.x * blockDim.x + threadIdx.x;
    if (i < n) rnorm[i] = rsqrtf((float)(cnt[i] + 1));
}

__global__ void scan1_kernel(const int* __restrict__ cnt, int* __restrict__ rowptr,
                             int* __restrict__ bsum, int n) {
    __shared__ int s[1024];
    int t = threadIdx.x;
    int i = blockIdx.x * 1024 + t;
    int v = (i < n) ? cnt[i] : 0;
    s[t] = v;
    __syncthreads();
    for (int off = 1; off < 1024; off <<= 1) {
        int x = (t >= off) ? s[t - off] : 0;
        __syncthreads();
        s[t] += x;
        __syncthreads();
    }
    if (i < n) rowptr[i] = s[t] - v;
    if (t == 1023) bsum[blockIdx.x] = s[1023];
}

__global__ void scan2_kernel(int* bsum, int nb) {
    if (threadIdx.x == 0 && blockIdx.x == 0) {
        int a = 0;
        for (int b = 0; b < nb; ++b) { int v = bsum[b]; bsum[b] = a; a += v; }
    }
}

__global__ void scan3_kernel(int* __restrict__ rowptr, const int* __restrict__ bsum, int n, int e) {
    int i = blockIdx.x * blockDim.x + threadIdx.x;
    if (i < n) rowptr[i] += bsum[i >> 10];
    if (i == 0) rowptr[n] = e;
}

__global__ void fill_kernel(const int* __restrict__ row, const int* __restrict__ col,
                            const int* __restrict__ rowptr, int* __restrict__ fillc,
                            const float* __restrict__ rnorm,
                            int2* __restrict__ meta, int e) {
    int i = blockIdx.x * blockDim.x + threadIdx.x;
    if (i >= e) return;
    int r = row[i], c = col[i];
    int pos = rowptr[r] + atomicAdd(&fillc[r], 1);
    float w = rnorm[r] * rnorm[c];
    meta[pos] = make_int2(c, __float_as_int(w));
}

// fp32 -> (bf16 hi, bf16 lo) elementwise, 4 at a time
__global__ void split_kernel(const float* __restrict__ in,
                             unsigned short* __restrict__ hi,
                             unsigned short* __restrict__ lo, int total4) {
    int i = blockIdx.x * blockDim.x + threadIdx.x;
    if (i >= total4) return;
    f32x4 x = *(const f32x4*)(in + (size_t)i * 4);
    s16x4 h, l;
#pragma unroll
    for (int q = 0; q < 4; ++q) {
        unsigned short hb = f2bf(x[q]);
        h[q] = (short)hb;
        l[q] = (short)f2bf(x[q] - bf2f(hb));
    }
    *(s16x4*)(hi + (size_t)i * 4) = h;
    *(s16x4*)(lo + (size_t)i * 4) = l;
}

template <int WPL> struct VecT;
template <> struct VecT<4> { using T = f32x4; };
template <> struct VecT<2> { using T = f32x2; };

// one wave per row; 64 lanes x WPL floats. Bias + optional gelu fused.
// SPLIT: write bf16 hi/lo pair (for the MFMA dense) instead of fp32.
template <int WPL, bool GELU, bool SPLIT>
__global__ __launch_bounds__(256) void spmm_kernel(const float* __restrict__ in,
                                                   float* __restrict__ out,
                                                   unsigned short* __restrict__ ohi,
                                                   unsigned short* __restrict__ olo,
                                                   const int* __restrict__ rowptr,
                                                   const int2* __restrict__ meta,
                                                   const float* __restrict__ rnorm,
                                                   const float* __restrict__ bias, int n) {
    using vec_t = typename VecT<WPL>::T;
    constexpr int RW = 64 * WPL;
    int wid = blockIdx.x * 4 + (threadIdx.x >> 6);
    if (wid >= n) return;
    int lane = threadIdx.x & 63;
    const float* lanebase = in + lane * WPL;

    float rn = rnorm[wid];
    float sw = rn * rn;   // self-loop weight
    float acc[WPL];
    {
        vec_t a = *(const vec_t*)(lanebase + (size_t)wid * RW);
#pragma unroll
        for (int q = 0; q < WPL; ++q) acc[q] = sw * a[q];
    }

    int e0 = rowptr[wid], e1 = rowptr[wid + 1];
    int e = e0;
    int nbatch = (e1 - e0) >> 3;
    if (nbatch > 0) {
        int2 m[8];
#pragma unroll
        for (int u = 0; u < 8; ++u) m[u] = meta[e + u];
        for (int b = 0; b < nbatch; ++b) {
            vec_t v[8];
#pragma unroll
            for (int u = 0; u < 8; ++u) v[u] = *(const vec_t*)(lanebase + (size_t)m[u].x * RW);
            int2 mn[8];
            bool more = (b + 1 < nbatch);
            if (more) {
#pragma unroll
                for (int u = 0; u < 8; ++u) mn[u] = meta[e + 8 + u];
            }
#pragma unroll
            for (int u = 0; u < 8; ++u) {
                float w = __int_as_float(m[u].y);
#pragma unroll
                for (int q = 0; q < WPL; ++q) acc[q] = fmaf(w, v[u][q], acc[q]);
            }
            if (more) {
#pragma unroll
                for (int u = 0; u < 8; ++u) m[u] = mn[u];
            }
            e += 8;
        }
    }
    for (; e < e1; ++e) {
        int2 m = meta[e];
        vec_t v = *(const vec_t*)(lanebase + (size_t)m.x * RW);
        float w = __int_as_float(m.y);
#pragma unroll
        for (int q = 0; q < WPL; ++q) acc[q] = fmaf(w, v[q], acc[q]);
    }

    vec_t bv = *(const vec_t*)(bias + lane * WPL);
    if (SPLIT) {
        s16x4 h, l;
#pragma unroll
        for (int q = 0; q < WPL; ++q) {
            float x = acc[q] + bv[q];
            float y = GELU ? gelu_fast(x) : x;
            unsigned short hb = f2bf(y);
            h[q] = (short)hb;
            l[q] = (short)f2bf(y - bf2f(hb));
        }
        *(s16x4*)(ohi + (size_t)wid * RW + lane * WPL) = h;
        *(s16x4*)(olo + (size_t)wid * RW + lane * WPL) = l;
    } else {
        vec_t o;
#pragma unroll
        for (int q = 0; q < WPL; ++q) {
            float x = acc[q] + bv[q];
            o[q] = GELU ? gelu_fast(x) : x;
        }
        __builtin_nontemporal_store(o, (vec_t*)(out + (size_t)wid * RW + lane * WPL));
    }
}

// out[N][DO] = (Ahi+Alo)[N][256] @ (Whi+Wlo)[DO][256]^T via 3 bf16 MFMAs.
// Block: 256 thr / 4 waves, 16 rows per wave (BM=64).
// W hi/lo staged per 64-k chunk into LDS, FRAGMENT-MAJOR: slot [frag][lane]
// holds the exact 16B that lane consumes -> ds_read_b128 conflict-free.
// Fragment layouts (gfx950 16x16x32 bf16):
//   A: row=lane&15, k=(lane>>4)*8+j ; B: col=lane&15, same k  -> B reads
//   W[n][k] natively. C: col=lane&15, row=(lane>>4)*4+reg.
template <int DO>
__global__ __launch_bounds__(256) void dense_mfma_kernel(
        const unsigned short* __restrict__ Ahi, const unsigned short* __restrict__ Alo,
        const unsigned short* __restrict__ Whi, const unsigned short* __restrict__ Wlo,
        float* __restrict__ out, int n) {
    constexpr int NT = DO / 16;          // n-tiles: 16 / 8
    constexpr int KC = 64;               // k per chunk
    constexpr int NKK = KC / 32;         // 2 MFMA k-steps per chunk
    constexpr int NCH = 256 / KC;        // 4 chunks
    constexpr int NFRAG = 2 * NT * NKK;  // hi+lo frags per chunk
    __shared__ bf16x8 s_w[NFRAG * 64];   // 64KB (DO=256) / 32KB (DO=128)

    int t = threadIdx.x;
    int lane = t & 63;
    int w = t >> 6;
    int row0 = blockIdx.x * 64;

    int arow = row0 + w * 16 + (lane & 15);
    if (arow > n - 1) arow = n - 1;                       // clamp (tail block)
    size_t aoff = (size_t)arow * 256 + ((lane >> 4) << 3);

    f32x4 acc[NT];
#pragma unroll
    for (int nt = 0; nt < NT; ++nt) acc[nt] = (f32x4){0.f, 0.f, 0.f, 0.f};

    for (int c = 0; c < NCH; ++c) {
        int k0 = c * KC;
        __syncthreads();
        // stage W hi/lo fragments for this k-chunk
#pragma unroll
        for (int i = 0; i < (NFRAG * 64) / 256; ++i) {
            int s = t + i * 256;
            int sl = s & 63;
            int f = s >> 6;                  // f = op*NT*NKK + nt*NKK + kk
            int kk = f % NKK;
            int ntf = (f / NKK) % NT;
            int op = f / (NKK * NT);
            const unsigned short* src = op ? Wlo : Whi;
            s_w[s] = *(const bf16x8*)&src[(size_t)(ntf * 16 + (sl & 15)) * 256
                                          + k0 + kk * 32 + ((sl >> 4) << 3)];
        }
        __syncthreads();

        bf16x8 ah[NKK], al[NKK];
#pragma unroll
        for (int kk = 0; kk < NKK; ++kk) {
            ah[kk] = *(const bf16x8*)&Ahi[aoff + k0 + kk * 32];
            al[kk] = *(const bf16x8*)&Alo[aoff + k0 + kk * 32];
        }
#pragma unroll
        for (int nt = 0; nt < NT; ++nt) {
#pragma unroll
            for (int kk = 0; kk < NKK; ++kk) {
                bf16x8 whi = s_w[(nt * NKK + kk) * 64 + lane];
                bf16x8 wlo = s_w[(NT * NKK + nt * NKK + kk) * 64 + lane];
                acc[nt] = __builtin_amdgcn_mfma_f32_16x16x32_bf16(ah[kk], whi, acc[nt], 0, 0, 0);
                acc[nt] = __builtin_amdgcn_mfma_f32_16x16x32_bf16(ah[kk], wlo, acc[nt], 0, 0, 0);
                acc[nt] = __builtin_amdgcn_mfma_f32_16x16x32_bf16(al[kk], whi, acc[nt], 0, 0, 0);
            }
        }
    }

    int crow0 = row0 + w * 16 + ((lane >> 4) << 2);
    int ccol = lane & 15;
#pragma unroll
    for (int nt = 0; nt < NT; ++nt) {
#pragma unroll
        for (int j = 0; j < 4; ++j) {
            int r = crow0 + j;
            if (r < n) out[(size_t)r * DO + nt * 16 + ccol] = acc[nt][j];
        }
    }
}

extern "C" void kernel_launch(void* const* d_in, const int* in_sizes, int n_in,
                              void* d_out, int out_size, void* d_ws, size_t ws_size,
                              hipStream_t stream) {
    const float* X  = (const float*)d_in[0];
    const int* row  = (const int*)d_in[1];
    const int* col  = (const int*)d_in[2];
    const float* W0 = (const float*)d_in[3];
    const float* b0 = (const float*)d_in[4];
    const float* W1 = (const float*)d_in[5];
    const float* b1 = (const float*)d_in[6];
    const float* W2 = (const float*)d_in[7];
    const float* b2 = (const float*)d_in[8];

    int n = in_sizes[0] / 256;   // 100000
    int e = in_sizes[1];         // 1600000

    char* ws = (char*)d_ws;
    size_t off = 0;
    auto alloc = [&](size_t bytes) {
        void* p = ws + off;
        off += (bytes + 255) & ~(size_t)255;
        return p;
    };
    unsigned short* HI   = (unsigned short*)alloc((size_t)n * 256 * 2);
    unsigned short* LO   = (unsigned short*)alloc((size_t)n * 256 * 2);
    float*          D    = (float*)alloc((size_t)n * 256 * 4);
    unsigned short* W0hi = (unsigned short*)alloc(256 * 256 * 2);
    unsigned short* W0lo = (unsigned short*)alloc(256 * 256 * 2);
    unsigned short* W1hi = (unsigned short*)alloc(256 * 256 * 2);
    unsigned short* W1lo = (unsigned short*)alloc(256 * 256 * 2);
    unsigned short* W2hi = (unsigned short*)alloc(256 * 128 * 2);
    unsigned short* W2lo = (unsigned short*)alloc(256 * 128 * 2);
    int*   cnt    = (int*)alloc((size_t)n * 4);
    int*   fillc  = (int*)alloc((size_t)n * 4);
    float* rnorm  = (float*)alloc((size_t)n * 4);
    int*   rowptr = (int*)alloc(((size_t)n + 1) * 4);
    int*   bsum   = (int*)alloc(512);
    int2*  meta   = (int2*)alloc((size_t)e * 8);

    (void)hipMemsetAsync(cnt, 0, (size_t)n * 4, stream);
    (void)hipMemsetAsync(fillc, 0, (size_t)n * 4, stream);

    int gE = (e + 255) / 256;
    int gN = (n + 255) / 256;
    int nb = (n + 1023) / 1024;

    count_kernel<<<gE, 256, 0, stream>>>(row, cnt, e);
    rnorm_kernel<<<gN, 256, 0, stream>>>(cnt, rnorm, n);
    scan1_kernel<<<nb, 1024, 0, stream>>>(cnt, rowptr, bsum, n);
    scan2_kernel<<<1, 64, 0, stream>>>(bsum, nb);
    scan3_kernel<<<gN, 256, 0, stream>>>(rowptr, bsum, n, e);
    fill_kernel<<<gE, 256, 0, stream>>>(row, col, rowptr, fillc, rnorm, meta, e);

    // splits: X (fused splits handle later activations), W0/W1/W2
    split_kernel<<<((n * 64) + 255) / 256, 256, 0, stream>>>(X, HI, LO, n * 64);
    split_kernel<<<(16384 + 255) / 256, 256, 0, stream>>>(W0, W0hi, W0lo, 16384);
    split_kernel<<<(16384 + 255) / 256, 256, 0, stream>>>(W1, W1hi, W1lo, 16384);
    split_kernel<<<(8192 + 255) / 256, 256, 0, stream>>>(W2, W2hi, W2lo, 8192);

    int gS = (n + 3) / 4;       // spmm: 4 waves/block, 1 row/wave
    int gM = (n + 63) / 64;     // dense mfma: 64 rows/block

    // D0 = X @ W0T ; A = gelu(spmm(D0)+b0) -> split bf16
    dense_mfma_kernel<256><<<gM, 256, 0, stream>>>(HI, LO, W0hi, W0lo, D, n);
    spmm_kernel<4, true, true><<<gS, 256, 0, stream>>>(D, nullptr, HI, LO, rowptr, meta, rnorm, b0, n);
    // D1 ; B = gelu(spmm(D1)+b1) -> split bf16
    dense_mfma_kernel<256><<<gM, 256, 0, stream>>>(HI, LO, W1hi, W1lo, D, n);
    spmm_kernel<4, true, true><<<gS, 256, 0, stream>>>(D, nullptr, HI, LO, rowptr, meta, rnorm, b1, n);
    // D2 (128-wide) ; out = spmm(D2) + b2 (fp32)
    dense_mfma_kernel<128><<<gM, 256, 0, stream>>>(HI, LO, W2hi, W2lo, D, n);
    spmm_kernel<2, false, false><<<gS, 256, 0, stream>>>(D, (float*)d_out, nullptr, nullptr, rowptr, meta, rnorm, b2, n);
}